// Round 1
// baseline (23016.525 us; speedup 1.0000x reference)
//
#include <hip/hip_runtime.h>
#include <math.h>

#define VOCAB 1000
#define EMB   128
#define HID   256
#define G4    1024   // 4*HID
#define BATCH 64
#define SEQT  1024

__device__ __forceinline__ float sigmoidf_(float x) {
    return 1.f / (1.f + __expf(-x));
}
__device__ __forceinline__ float tanhf_(float x) {
    // 1 - 2/(e^{2x}+1); saturates correctly at +-inf
    return 1.f - 2.f / (__expf(2.f * x) + 1.f);
}

// Kernel 1: eproj[v][g] = sum_e emb[v][e] * W_ih[g][e] + b_ih[g] + b_hh[g]
// Tiny (131M MACs). One block per vocab entry, one thread per gate.
__global__ __launch_bounds__(1024) void eproj_kernel(
    const float* __restrict__ emb, const float* __restrict__ W_ih,
    const float* __restrict__ b_ih, const float* __restrict__ b_hh,
    float* __restrict__ eproj)
{
    const int v = blockIdx.x;
    const int g = threadIdx.x;
    __shared__ __align__(16) float x_sh[EMB];
    if (g < EMB / 4) {
        ((float4*)x_sh)[g] = ((const float4*)(emb + (size_t)v * EMB))[g];
    }
    __syncthreads();
    const float4* wrow = (const float4*)(W_ih + (size_t)g * EMB);
    float a0 = 0.f, a1 = 0.f, a2 = 0.f, a3 = 0.f;
#pragma unroll
    for (int e4 = 0; e4 < EMB / 4; e4++) {
        float4 wv = wrow[e4];
        float4 xv = ((const float4*)x_sh)[e4];
        a0 += wv.x * xv.x;
        a1 += wv.y * xv.y;
        a2 += wv.z * xv.z;
        a3 += wv.w * xv.w;
    }
    eproj[(size_t)v * G4 + g] = (a0 + a1) + (a2 + a3) + b_ih[g] + b_hh[g];
}

// Kernel 2: persistent LSTM, one block per batch element (one CU each).
// Thread t owns gate-row t of W_hh in registers (256 f32). h/c/gates in LDS.
// USE_EPROJ=false is a correctness fallback if ws is too small for the table.
template <bool USE_EPROJ>
__global__ __launch_bounds__(1024, 1) void lstm_kernel(
    const int* __restrict__ ids, const int* __restrict__ lens,
    const float* __restrict__ eproj,
    const float* __restrict__ emb, const float* __restrict__ W_ih,
    const float* __restrict__ b_ih, const float* __restrict__ b_hh,
    const float* __restrict__ W_hh, float* __restrict__ out)
{
    const int b = blockIdx.x;
    const int t = threadIdx.x;   // gate index 0..1023 (i:0-255 f:256-511 g:512-767 o:768-1023)

    __shared__ __align__(16) float h_sh[HID];
    __shared__ __align__(16) float c_sh[HID];
    __shared__ __align__(16) float gates[G4];
    __shared__ __align__(16) float x_sh[EMB];   // fallback path only

    // --- W_hh row t into registers (one-time, L2-served across 64 blocks) ---
    float w[HID];
    {
        const float4* wrow = (const float4*)(W_hh + (size_t)t * HID);
#pragma unroll
        for (int k4 = 0; k4 < HID / 4; k4++) {
            float4 wv = wrow[k4];
            w[4 * k4 + 0] = wv.x;
            w[4 * k4 + 1] = wv.y;
            w[4 * k4 + 2] = wv.z;
            w[4 * k4 + 3] = wv.w;
        }
    }

    float wih[EMB];   // fallback path only; dead (eliminated) when USE_EPROJ
    float bias = 0.f;
    if constexpr (!USE_EPROJ) {
        const float4* wr = (const float4*)(W_ih + (size_t)t * EMB);
#pragma unroll
        for (int e4 = 0; e4 < EMB / 4; e4++) {
            float4 wv = wr[e4];
            wih[4 * e4 + 0] = wv.x;
            wih[4 * e4 + 1] = wv.y;
            wih[4 * e4 + 2] = wv.z;
            wih[4 * e4 + 3] = wv.w;
        }
        bias = b_ih[t] + b_hh[t];
    }

    const int len = lens[b];                 // >= 1 by construction
    const int* ids_row = ids + (size_t)b * SEQT;

    if (t < HID) { h_sh[t] = 0.f; c_sh[t] = 0.f; }

    float xw = 0.f;
    if constexpr (USE_EPROJ) {
        // prefetch step 0's input-projection value for this gate
        int id0 = ids_row[0];
        xw = eproj[(size_t)id0 * G4 + t];
    }
    __syncthreads();

    for (int step = 0; step < len; step++) {
        float acc;
        if constexpr (USE_EPROJ) {
            acc = xw;
            // prefetch next step's value; consumed after the 2048-cyc k-loop
            int nstep = (step + 1 < len) ? (step + 1) : (len - 1);
            int idn = ids_row[nstep];
            xw = eproj[(size_t)idn * G4 + t];
        } else {
            // stage emb row for this step, then dot with registered W_ih row
            int id = ids_row[step];
            if (t < EMB / 4) {
                ((float4*)x_sh)[t] = ((const float4*)(emb + (size_t)id * EMB))[t];
            }
            __syncthreads();
            float a0 = bias, a1 = 0.f, a2 = 0.f, a3 = 0.f;
#pragma unroll
            for (int e4 = 0; e4 < EMB / 4; e4++) {
                float4 xv = ((const float4*)x_sh)[e4];
                a0 += wih[4 * e4 + 0] * xv.x;
                a1 += wih[4 * e4 + 1] * xv.y;
                a2 += wih[4 * e4 + 2] * xv.z;
                a3 += wih[4 * e4 + 3] * xv.w;
            }
            acc = (a0 + a1) + (a2 + a3);
        }

        // gate_t = acc + w . h      (h broadcast-read from LDS, float4)
        float a0 = acc, a1 = 0.f, a2 = 0.f, a3 = 0.f;
#pragma unroll
        for (int k4 = 0; k4 < HID / 4; k4++) {
            float4 hv = ((const float4*)h_sh)[k4];
            a0 += w[4 * k4 + 0] * hv.x;
            a1 += w[4 * k4 + 1] * hv.y;
            a2 += w[4 * k4 + 2] * hv.z;
            a3 += w[4 * k4 + 3] * hv.w;
        }
        gates[t] = (a0 + a1) + (a2 + a3);
        __syncthreads();

        if (t < HID) {
            float ig = sigmoidf_(gates[t]);
            float fg = sigmoidf_(gates[HID + t]);
            float gg = tanhf_(gates[2 * HID + t]);
            float og = sigmoidf_(gates[3 * HID + t]);
            float c = fg * c_sh[t] + ig * gg;
            c_sh[t] = c;
            h_sh[t] = og * tanhf_(c);
        }
        __syncthreads();
    }

    if (t < HID) out[(size_t)b * HID + t] = h_sh[t];
}

extern "C" void kernel_launch(void* const* d_in, const int* in_sizes, int n_in,
                              void* d_out, int out_size, void* d_ws, size_t ws_size,
                              hipStream_t stream) {
    const int*   ids  = (const int*)d_in[0];
    const int*   lens = (const int*)d_in[1];
    const float* emb  = (const float*)d_in[2];
    const float* Wih  = (const float*)d_in[3];
    const float* Whh  = (const float*)d_in[4];
    const float* bih  = (const float*)d_in[5];
    const float* bhh  = (const float*)d_in[6];
    float* out = (float*)d_out;

    const size_t eproj_bytes = (size_t)VOCAB * G4 * sizeof(float);
    if (ws_size >= eproj_bytes) {
        float* eproj = (float*)d_ws;
        eproj_kernel<<<VOCAB, 1024, 0, stream>>>(emb, Wih, bih, bhh, eproj);
        lstm_kernel<true><<<BATCH, 1024, 0, stream>>>(
            ids, lens, eproj, emb, Wih, bih, bhh, Whh, out);
    } else {
        lstm_kernel<false><<<BATCH, 1024, 0, stream>>>(
            ids, lens, nullptr, emb, Wih, bih, bhh, Whh, out);
    }
}

// Round 2
// 4461.354 us; speedup vs baseline: 5.1591x; 5.1591x over previous
//
#include <hip/hip_runtime.h>
#include <math.h>

#define VOCAB 1000
#define EMB   128
#define HID   256
#define G4    1024   // 4*HID
#define BATCH 64
#define SEQT  1024
#define CHUNK 64     // hidden units per block
#define NBLK  4      // blocks per batch element

__device__ __forceinline__ float sigmoidf_(float x) {
    return 1.f / (1.f + __expf(-x));
}
__device__ __forceinline__ float tanhf_(float x) {
    return 1.f - 2.f / (__expf(2.f * x) + 1.f);
}

// ---------------------------------------------------------------------------
// Kernel 1: eproj[v][g] = emb[v] . W_ih[g] + b_ih[g] + b_hh[g]   (131M MACs)
// ---------------------------------------------------------------------------
__global__ __launch_bounds__(1024) void eproj_kernel(
    const float* __restrict__ emb, const float* __restrict__ W_ih,
    const float* __restrict__ b_ih, const float* __restrict__ b_hh,
    float* __restrict__ eproj)
{
    const int v = blockIdx.x;
    const int g = threadIdx.x;
    __shared__ __align__(16) float x_sh[EMB];
    if (g < EMB / 4) {
        ((float4*)x_sh)[g] = ((const float4*)(emb + (size_t)v * EMB))[g];
    }
    __syncthreads();
    const float4* wrow = (const float4*)(W_ih + (size_t)g * EMB);
    float a0 = 0.f, a1 = 0.f, a2 = 0.f, a3 = 0.f;
#pragma unroll
    for (int e4 = 0; e4 < EMB / 4; e4++) {
        float4 wv = wrow[e4];
        float4 xv = ((const float4*)x_sh)[e4];
        a0 += wv.x * xv.x;
        a1 += wv.y * xv.y;
        a2 += wv.z * xv.z;
        a3 += wv.w * xv.w;
    }
    eproj[(size_t)v * G4 + g] = (a0 + a1) + (a2 + a3) + b_ih[g] + b_hh[g];
}

// ---------------------------------------------------------------------------
// Kernel 2: 4 blocks per batch element, 256 threads each (1 wave/SIMD ->
// 512-VGPR budget so the 256-f32 W_hh row stays register-resident).
// Block s of group b owns hidden units [64s, 64s+64): it computes gate rows
// {g*256 + 64s + u} for g in {i,f,g,o}, so c stays local and only 64 h
// values are exchanged per step via agent-scope atomics (double-buffered).
// blockIdx mapping: idx = xcd + 8*(4*slot + s)  -> the 4 blocks of a group
// share blockIdx%8 (same-XCD under round-robin) and group (xcd=0,slot=0)
// completes within the first 25 blocks of any in-order dispatch prefix.
// ---------------------------------------------------------------------------
__global__ __launch_bounds__(256, 1) void lstm_group_kernel(
    const int* __restrict__ ids, const int* __restrict__ lens,
    const float* __restrict__ eproj, const float* __restrict__ W_hh,
    float* __restrict__ hx,      // [2][BATCH][NBLK*CHUNK]
    int* __restrict__ flags,     // [BATCH][NBLK]
    float* __restrict__ out)
{
    const int idx  = blockIdx.x;
    const int xcd  = idx & 7;
    const int m    = idx >> 3;     // 0..31
    const int s    = m & 3;        // chunk 0..3
    const int slot = m >> 2;       // 0..7
    const int b    = xcd + 8 * slot;   // batch element 0..63

    const int j  = threadIdx.x;    // 0..255
    const int gt = j >> 6;         // gate type 0..3 (i,f,g,o)
    const int ul = j & 63;         // unit-local 0..63
    const int r  = (gt << 8) | (s << 6) | ul;   // gate row 0..1023

    __shared__ __align__(16) float h_sh[HID];
    __shared__ __align__(16) float gates_sh[256];

    // W_hh row r -> registers (one-time; ~290 VGPRs total, spill-free)
    float w[HID];
    {
        const float4* wrow = (const float4*)(W_hh + (size_t)r * HID);
#pragma unroll
        for (int k4 = 0; k4 < HID / 4; k4++) {
            float4 wv = wrow[k4];
            w[4 * k4 + 0] = wv.x;
            w[4 * k4 + 1] = wv.y;
            w[4 * k4 + 2] = wv.z;
            w[4 * k4 + 3] = wv.w;
        }
    }

    const int len = lens[b];                  // >= 1
    const int* ids_row = ids + (size_t)b * SEQT;

    h_sh[j] = 0.f;                            // j covers all 256 h entries
    float c = 0.f;                            // valid for j < 64

    float xw = eproj[(size_t)ids_row[0] * G4 + r];   // step-0 input proj
    __syncthreads();

    int*   flag_b  = flags + b * NBLK;
    const int hx_stride = BATCH * NBLK * CHUNK;

    for (int step = 0; step < len; step++) {
        // ---- gates: xw + w . h  (h broadcast float4 from LDS) ----
        float a0 = xw, a1 = 0.f, a2 = 0.f, a3 = 0.f;
#pragma unroll
        for (int k4 = 0; k4 < HID / 4; k4++) {
            float4 hv = ((const float4*)h_sh)[k4];
            a0 += w[4 * k4 + 0] * hv.x;
            a1 += w[4 * k4 + 1] * hv.y;
            a2 += w[4 * k4 + 2] * hv.z;
            a3 += w[4 * k4 + 3] * hv.w;
        }
        gates_sh[j] = (a0 + a1) + (a2 + a3);

        // prefetch next step's input projection (hides L2 gather latency)
        int nstep = (step + 1 < len) ? step + 1 : len - 1;
        xw = eproj[(size_t)ids_row[nstep] * G4 + r];

        __syncthreads();

        const bool last = (step + 1 >= len);
        float* hx_b = hx + (step & 1) * hx_stride + b * (NBLK * CHUNK);

        if (j < CHUNK) {
            float ig = sigmoidf_(gates_sh[j]);
            float fg = sigmoidf_(gates_sh[64 + j]);
            float gg = tanhf_(gates_sh[128 + j]);
            float og = sigmoidf_(gates_sh[192 + j]);
            c = fg * c + ig * gg;
            float h = og * tanhf_(c);
            h_sh[(s << 6) | j] = h;
            if (!last) {
                __hip_atomic_store(&hx_b[(s << 6) | j], h,
                                   __ATOMIC_RELAXED, __HIP_MEMORY_SCOPE_AGENT);
            }
        }
        __syncthreads();   // barrier drains vmem stores before flag release

        if (!last) {
            if (j == 0) {
                __hip_atomic_store(&flag_b[s], step + 1,
                                   __ATOMIC_RELEASE, __HIP_MEMORY_SCOPE_AGENT);
            }
            if (j < NBLK && j != s) {
                // poison 0xAAAAAAAA is negative as signed -> treated not-ready
                while (__hip_atomic_load(&flag_b[j], __ATOMIC_ACQUIRE,
                                         __HIP_MEMORY_SCOPE_AGENT) < step + 1) {
                    __builtin_amdgcn_s_sleep(1);
                }
            }
            __syncthreads();
            // gather the 3 partner chunks (acquire above invalidated L1)
            if ((j >> 6) != s) {
                h_sh[j] = __hip_atomic_load(&hx_b[j], __ATOMIC_RELAXED,
                                            __HIP_MEMORY_SCOPE_AGENT);
            }
            __syncthreads();
        }
    }

    if (j < CHUNK) {
        out[(size_t)b * HID + ((s << 6) | j)] = h_sh[(s << 6) | j];
    }
}

// ---------------------------------------------------------------------------
// Fallback (ws too small): correct-but-slow single-block version.
// ---------------------------------------------------------------------------
__global__ __launch_bounds__(1024, 1) void lstm_fallback(
    const int* __restrict__ ids, const int* __restrict__ lens,
    const float* __restrict__ emb, const float* __restrict__ W_ih,
    const float* __restrict__ b_ih, const float* __restrict__ b_hh,
    const float* __restrict__ W_hh, float* __restrict__ out)
{
    const int b = blockIdx.x;
    const int t = threadIdx.x;

    __shared__ __align__(16) float h_sh[HID];
    __shared__ __align__(16) float c_sh[HID];
    __shared__ __align__(16) float gates[G4];
    __shared__ __align__(16) float x_sh[EMB];

    float wih[EMB];
    {
        const float4* wr = (const float4*)(W_ih + (size_t)t * EMB);
#pragma unroll
        for (int e4 = 0; e4 < EMB / 4; e4++) {
            float4 wv = wr[e4];
            wih[4 * e4 + 0] = wv.x;
            wih[4 * e4 + 1] = wv.y;
            wih[4 * e4 + 2] = wv.z;
            wih[4 * e4 + 3] = wv.w;
        }
    }
    float bias = b_ih[t] + b_hh[t];

    const int len = lens[b];
    const int* ids_row = ids + (size_t)b * SEQT;
    if (t < HID) { h_sh[t] = 0.f; c_sh[t] = 0.f; }
    __syncthreads();

    for (int step = 0; step < len; step++) {
        int id = ids_row[step];
        if (t < EMB / 4) {
            ((float4*)x_sh)[t] = ((const float4*)(emb + (size_t)id * EMB))[t];
        }
        __syncthreads();
        float a0 = bias, a1 = 0.f, a2 = 0.f, a3 = 0.f;
#pragma unroll
        for (int e4 = 0; e4 < EMB / 4; e4++) {
            float4 xv = ((const float4*)x_sh)[e4];
            a0 += wih[4 * e4 + 0] * xv.x;
            a1 += wih[4 * e4 + 1] * xv.y;
            a2 += wih[4 * e4 + 2] * xv.z;
            a3 += wih[4 * e4 + 3] * xv.w;
        }
        float acc = (a0 + a1) + (a2 + a3);

        const float* wrow = W_hh + (size_t)t * HID;
        a0 = acc; a1 = 0.f; a2 = 0.f; a3 = 0.f;
        for (int k4 = 0; k4 < HID / 4; k4++) {
            float4 hv = ((const float4*)h_sh)[k4];
            float4 wv = ((const float4*)wrow)[k4];
            a0 += wv.x * hv.x;
            a1 += wv.y * hv.y;
            a2 += wv.z * hv.z;
            a3 += wv.w * hv.w;
        }
        gates[t] = (a0 + a1) + (a2 + a3);
        __syncthreads();

        if (t < HID) {
            float ig = sigmoidf_(gates[t]);
            float fg = sigmoidf_(gates[HID + t]);
            float gg = tanhf_(gates[2 * HID + t]);
            float og = sigmoidf_(gates[3 * HID + t]);
            float cc = fg * c_sh[t] + ig * gg;
            c_sh[t] = cc;
            h_sh[t] = og * tanhf_(cc);
        }
        __syncthreads();
    }
    if (t < HID) out[(size_t)b * HID + t] = h_sh[t];
}

extern "C" void kernel_launch(void* const* d_in, const int* in_sizes, int n_in,
                              void* d_out, int out_size, void* d_ws, size_t ws_size,
                              hipStream_t stream) {
    const int*   ids  = (const int*)d_in[0];
    const int*   lens = (const int*)d_in[1];
    const float* emb  = (const float*)d_in[2];
    const float* Wih  = (const float*)d_in[3];
    const float* Whh  = (const float*)d_in[4];
    const float* bih  = (const float*)d_in[5];
    const float* bhh  = (const float*)d_in[6];
    float* out = (float*)d_out;

    // workspace layout: flags[64][4] | hx[2][64][256] | eproj[1000][1024]
    const size_t flags_bytes = (size_t)BATCH * NBLK * sizeof(int);     // 1 KB
    const size_t hx_off      = 1024;
    const size_t hx_bytes    = (size_t)2 * BATCH * NBLK * CHUNK * sizeof(float); // 128 KB
    const size_t ep_off      = hx_off + hx_bytes;                       // 132096 (512B-aligned)
    const size_t ep_bytes    = (size_t)VOCAB * G4 * sizeof(float);      // 4 MB
    (void)flags_bytes;

    if (ws_size >= ep_off + ep_bytes) {
        int*   flags = (int*)d_ws;
        float* hx    = (float*)((char*)d_ws + hx_off);
        float* eproj = (float*)((char*)d_ws + ep_off);
        eproj_kernel<<<VOCAB, 1024, 0, stream>>>(emb, Wih, bih, bhh, eproj);
        lstm_group_kernel<<<BATCH * NBLK, 256, 0, stream>>>(
            ids, lens, eproj, Whh, hx, flags, out);
    } else {
        lstm_fallback<<<BATCH, 1024, 0, stream>>>(
            ids, lens, emb, Wih, bih, bhh, Whh, out);
    }
}

// Round 3
// 3430.912 us; speedup vs baseline: 6.7086x; 1.3003x over previous
//
#include <hip/hip_runtime.h>
#include <math.h>

#define VOCAB 1000
#define EMB   128
#define HID   256
#define G4    1024   // 4*HID
#define BATCH 64
#define SEQT  1024
#define CHUNK 64     // hidden units per block
#define NBLK  4      // blocks per batch element

__device__ __forceinline__ float sigmoidf_(float x) {
    return 1.f / (1.f + __expf(-x));
}
__device__ __forceinline__ float tanhf_(float x) {
    return 1.f - 2.f / (__expf(2.f * x) + 1.f);
}

// ---------------------------------------------------------------------------
// Kernel 1: eproj[v][g] = emb[v] . W_ih[g] + b_ih[g] + b_hh[g]   (131M MACs)
// ---------------------------------------------------------------------------
__global__ __launch_bounds__(1024) void eproj_kernel(
    const float* __restrict__ emb, const float* __restrict__ W_ih,
    const float* __restrict__ b_ih, const float* __restrict__ b_hh,
    float* __restrict__ eproj)
{
    const int v = blockIdx.x;
    const int g = threadIdx.x;
    __shared__ __align__(16) float x_sh[EMB];
    if (g < EMB / 4) {
        ((float4*)x_sh)[g] = ((const float4*)(emb + (size_t)v * EMB))[g];
    }
    __syncthreads();
    const float4* wrow = (const float4*)(W_ih + (size_t)g * EMB);
    float a0 = 0.f, a1 = 0.f, a2 = 0.f, a3 = 0.f;
#pragma unroll
    for (int e4 = 0; e4 < EMB / 4; e4++) {
        float4 wv = wrow[e4];
        float4 xv = ((const float4*)x_sh)[e4];
        a0 += wv.x * xv.x;
        a1 += wv.y * xv.y;
        a2 += wv.z * xv.z;
        a3 += wv.w * xv.w;
    }
    eproj[(size_t)v * G4 + g] = (a0 + a1) + (a2 + a3) + b_ih[g] + b_hh[g];
}

// ---------------------------------------------------------------------------
// Kernel 2: 4 blocks per batch element, 256 threads each. Thread owns gate
// row r = gt*256 + s*64 + ul of W_hh in registers (AGPR-backed, no scratch).
// Cross-block h exchange: ONE packed 64-bit relaxed atomic per h value
// (tag<<32 | float_bits) -- data travels with its own readiness tag, so no
// release/acquire fences, no flag indirection, no separate gather. Parity
// double-buffer makes slot reuse safe (slot of tag t+1 can only be
// overwritten at t+3, which requires every consumer to have read t+1).
// ---------------------------------------------------------------------------
__global__ __launch_bounds__(256, 1) void lstm_group_kernel(
    const int* __restrict__ ids, const int* __restrict__ lens,
    const float* __restrict__ eproj, const float* __restrict__ W_hh,
    unsigned long long* __restrict__ hx,   // [2][BATCH][HID] packed (tag,h)
    float* __restrict__ out)
{
    const int idx  = blockIdx.x;
    const int xcd  = idx & 7;
    const int m    = idx >> 3;     // 0..31
    const int s    = m & 3;        // chunk 0..3
    const int slot = m >> 2;       // 0..7
    const int b    = xcd + 8 * slot;   // batch element 0..63

    const int j  = threadIdx.x;    // 0..255
    const int gt = j >> 6;         // gate type 0..3 (i,f,g,o)
    const int ul = j & 63;         // unit-local 0..63
    const int r  = (gt << 8) | (s << 6) | ul;   // gate row 0..1023

    __shared__ __align__(16) float h_sh[HID];
    __shared__ __align__(16) float gates_sh[256];

    // W_hh row r -> registers (one-time; AGPR-backed on gfx950 unified file)
    float w[HID];
    {
        const float4* wrow = (const float4*)(W_hh + (size_t)r * HID);
#pragma unroll
        for (int k4 = 0; k4 < HID / 4; k4++) {
            float4 wv = wrow[k4];
            w[4 * k4 + 0] = wv.x;
            w[4 * k4 + 1] = wv.y;
            w[4 * k4 + 2] = wv.z;
            w[4 * k4 + 3] = wv.w;
        }
    }

    const int len = lens[b];                  // >= 1
    const int* ids_row = ids + (size_t)b * SEQT;

    h_sh[j] = 0.f;                            // j covers all 256 h entries
    float c = 0.f;                            // live in threads with gt==s
    float hlast = 0.f;

    float xw = eproj[(size_t)ids_row[0] * G4 + r];   // step-0 input proj
    __syncthreads();

    unsigned long long* hx_b = hx + (size_t)b * HID;
    const size_t par_stride = (size_t)BATCH * HID;

    for (int step = 0; step < len; step++) {
        // prefetch next step's input projection: latency hides under k-loop
        const int nstep = (step + 1 < len) ? step + 1 : len - 1;
        const float xw_next = eproj[(size_t)ids_row[nstep] * G4 + r];

        // ---- gates: xw + w . h  (h broadcast float4 from LDS) ----
        float a0 = xw, a1 = 0.f, a2 = 0.f, a3 = 0.f;
#pragma unroll
        for (int k4 = 0; k4 < HID / 4; k4++) {
            float4 hv = ((const float4*)h_sh)[k4];
            a0 += w[4 * k4 + 0] * hv.x;
            a1 += w[4 * k4 + 1] * hv.y;
            a2 += w[4 * k4 + 2] * hv.z;
            a3 += w[4 * k4 + 3] * hv.w;
        }
        gates_sh[j] = (a0 + a1) + (a2 + a3);
        __syncthreads();

        const bool last = (step + 1 >= len);
        unsigned long long* hq = hx_b + (size_t)(step & 1) * par_stride;

        if (gt == s) {
            // wave s: activation for own 64 units, publish packed (tag,h)
            float ig = sigmoidf_(gates_sh[ul]);
            float fg = sigmoidf_(gates_sh[64 + ul]);
            float gg = tanhf_(gates_sh[128 + ul]);
            float og = sigmoidf_(gates_sh[192 + ul]);
            c = fg * c + ig * gg;
            float h = og * tanhf_(c);
            hlast = h;
            h_sh[(s << 6) | ul] = h;
            if (!last) {
                union { float f; unsigned u; } cv; cv.f = h;
                unsigned long long pk =
                    ((unsigned long long)(unsigned)(step + 1) << 32) | cv.u;
                __hip_atomic_store(&hq[(s << 6) | ul], pk,
                                   __ATOMIC_RELAXED, __HIP_MEMORY_SCOPE_AGENT);
            }
        } else if (!last) {
            // wave gt polls partner chunk gt's packed words directly
            const unsigned want = (unsigned)(step + 1);
            unsigned long long v;
            do {
                v = __hip_atomic_load(&hq[(gt << 6) | ul],
                                      __ATOMIC_RELAXED, __HIP_MEMORY_SCOPE_AGENT);
            } while ((unsigned)(v >> 32) != want);
            union { unsigned u; float f; } cv; cv.u = (unsigned)v;
            h_sh[(gt << 6) | ul] = cv.f;
        }
        __syncthreads();
        xw = xw_next;
    }

    if (gt == s) {
        out[(size_t)b * HID + ((s << 6) | ul)] = hlast;
    }
}

// ---------------------------------------------------------------------------
// Fallback (ws too small): correct-but-slow single-block version.
// ---------------------------------------------------------------------------
__global__ __launch_bounds__(1024, 1) void lstm_fallback(
    const int* __restrict__ ids, const int* __restrict__ lens,
    const float* __restrict__ emb, const float* __restrict__ W_ih,
    const float* __restrict__ b_ih, const float* __restrict__ b_hh,
    const float* __restrict__ W_hh, float* __restrict__ out)
{
    const int b = blockIdx.x;
    const int t = threadIdx.x;

    __shared__ __align__(16) float h_sh[HID];
    __shared__ __align__(16) float c_sh[HID];
    __shared__ __align__(16) float gates[G4];
    __shared__ __align__(16) float x_sh[EMB];

    float wih[EMB];
    {
        const float4* wr = (const float4*)(W_ih + (size_t)t * EMB);
#pragma unroll
        for (int e4 = 0; e4 < EMB / 4; e4++) {
            float4 wv = wr[e4];
            wih[4 * e4 + 0] = wv.x;
            wih[4 * e4 + 1] = wv.y;
            wih[4 * e4 + 2] = wv.z;
            wih[4 * e4 + 3] = wv.w;
        }
    }
    float bias = b_ih[t] + b_hh[t];

    const int len = lens[b];
    const int* ids_row = ids + (size_t)b * SEQT;
    if (t < HID) { h_sh[t] = 0.f; c_sh[t] = 0.f; }
    __syncthreads();

    for (int step = 0; step < len; step++) {
        int id = ids_row[step];
        if (t < EMB / 4) {
            ((float4*)x_sh)[t] = ((const float4*)(emb + (size_t)id * EMB))[t];
        }
        __syncthreads();
        float a0 = bias, a1 = 0.f, a2 = 0.f, a3 = 0.f;
#pragma unroll
        for (int e4 = 0; e4 < EMB / 4; e4++) {
            float4 xv = ((const float4*)x_sh)[e4];
            a0 += wih[4 * e4 + 0] * xv.x;
            a1 += wih[4 * e4 + 1] * xv.y;
            a2 += wih[4 * e4 + 2] * xv.z;
            a3 += wih[4 * e4 + 3] * xv.w;
        }
        float acc = (a0 + a1) + (a2 + a3);

        const float* wrow = W_hh + (size_t)t * HID;
        a0 = acc; a1 = 0.f; a2 = 0.f; a3 = 0.f;
        for (int k4 = 0; k4 < HID / 4; k4++) {
            float4 hv = ((const float4*)h_sh)[k4];
            float4 wv = ((const float4*)wrow)[k4];
            a0 += wv.x * hv.x;
            a1 += wv.y * hv.y;
            a2 += wv.z * hv.z;
            a3 += wv.w * hv.w;
        }
        gates[t] = (a0 + a1) + (a2 + a3);
        __syncthreads();

        if (t < HID) {
            float ig = sigmoidf_(gates[t]);
            float fg = sigmoidf_(gates[HID + t]);
            float gg = tanhf_(gates[2 * HID + t]);
            float og = sigmoidf_(gates[3 * HID + t]);
            float cc = fg * c_sh[t] + ig * gg;
            c_sh[t] = cc;
            h_sh[t] = og * tanhf_(cc);
        }
        __syncthreads();
    }
    if (t < HID) out[(size_t)b * HID + t] = h_sh[t];
}

extern "C" void kernel_launch(void* const* d_in, const int* in_sizes, int n_in,
                              void* d_out, int out_size, void* d_ws, size_t ws_size,
                              hipStream_t stream) {
    const int*   ids  = (const int*)d_in[0];
    const int*   lens = (const int*)d_in[1];
    const float* emb  = (const float*)d_in[2];
    const float* Wih  = (const float*)d_in[3];
    const float* Whh  = (const float*)d_in[4];
    const float* bih  = (const float*)d_in[5];
    const float* bhh  = (const float*)d_in[6];
    float* out = (float*)d_out;

    // workspace layout: hx[2][64][256] packed u64 (256 KB) | eproj (4 MB)
    const size_t hx_bytes = (size_t)2 * BATCH * HID * sizeof(unsigned long long);
    const size_t ep_off   = hx_bytes;                       // 262144, aligned
    const size_t ep_bytes = (size_t)VOCAB * G4 * sizeof(float);

    if (ws_size >= ep_off + ep_bytes) {
        unsigned long long* hxq = (unsigned long long*)d_ws;
        float* eproj = (float*)((char*)d_ws + ep_off);
        eproj_kernel<<<VOCAB, 1024, 0, stream>>>(emb, Wih, bih, bhh, eproj);
        lstm_group_kernel<<<BATCH * NBLK, 256, 0, stream>>>(
            ids, lens, eproj, Whh, hxq, out);
    } else {
        lstm_fallback<<<BATCH, 1024, 0, stream>>>(
            ids, lens, emb, Wih, bih, bhh, Whh, out);
    }
}